// Round 9
// baseline (68.620 us; speedup 1.0000x reference)
//
#include <hip/hip_runtime.h>
#include <stdint.h>

// BERT input representation, round 9: DIAGNOSTIC — R4 pipeline verbatim, main
// kernel launched TWICE (idempotent). dur_R9 - dur_R4 = true marginal HW cost
// of one main pass, separating fixed replay overhead from kernel time.
//   out = x@W + seg + b_emb*(1+Sw) + b_seg + PE
// d_ws: [0,128KB) W bf16 A-frag | [128KB,+4MB) x bf16

typedef __attribute__((ext_vector_type(8))) short short8;
typedef __attribute__((ext_vector_type(4))) float f32x4;

#define D_DIM 1024
#define WS_X_OFF 131072

__device__ __forceinline__ unsigned short f2bf(float f) {
  unsigned u = __float_as_uint(f);
  u = (u + 0x7FFFu + ((u >> 16) & 1u)) >> 16;  // RNE f32 -> bf16
  return (unsigned short)u;
}

__global__ __launch_bounds__(256) void bert_setup(
    const float* __restrict__ x, const float* __restrict__ W,
    unsigned short* __restrict__ wsW, unsigned short* __restrict__ wsX) {
  const int bid = blockIdx.x;
  const int tid = threadIdx.x;
  if (bid < 1024) {
    // ---- x f32 -> bf16, 8 elems/thread ----
    const int t = bid * 256 + tid;
    const float4* p = reinterpret_cast<const float4*>(x) + (size_t)t * 2;
    float4 v0 = p[0], v1 = p[1];
    short8 o;
    o[0] = (short)f2bf(v0.x); o[1] = (short)f2bf(v0.y);
    o[2] = (short)f2bf(v0.z); o[3] = (short)f2bf(v0.w);
    o[4] = (short)f2bf(v1.x); o[5] = (short)f2bf(v1.y);
    o[6] = (short)f2bf(v1.z); o[7] = (short)f2bf(v1.w);
    *reinterpret_cast<short8*>(wsX + (size_t)t * 8) = o;
  } else {
    // ---- W -> bf16 A-fragment layout ----
    const int t = (bid - 1024) * 256 + tid;  // 0..8191
    const int cfg = t >> 7;
    const int kf = (t >> 6) & 1;
    const int lane = t & 63;
    const int col = cfg * 16 + (lane & 15);
    const int k0 = kf * 32 + ((lane >> 4) << 3);
    short8 o;
#pragma unroll
    for (int i = 0; i < 8; ++i)
      o[i] = (short)f2bf(W[(size_t)(k0 + i) * D_DIM + col]);
    *reinterpret_cast<short8*>(wsW + (size_t)t * 8) = o;
  }
}

__global__ __launch_bounds__(256) void bert_main(
    const unsigned short* __restrict__ wsX,
    const unsigned short* __restrict__ wsW, const float* __restrict__ b_emb,
    const float* __restrict__ w_seg, const float* __restrict__ b_seg,
    float* __restrict__ out) {
  const int tid = threadIdx.x;
  const int lane = tid & 63;
  const int wave = tid >> 6;
  const int bid = blockIdx.x;
  const int nblk = (bid >> 3) & 7;
  const int mblk = (bid & 7) | ((bid >> 6) << 3);
  const int mbase = mblk * 64;
  const int nbase = nblk * 128;
  const int mw = wave >> 1;
  const int nw = wave & 1;
  const int L15 = lane & 15;
  const int g = lane >> 4;

  short8 aW[4][2];
#pragma unroll
  for (int cf = 0; cf < 4; ++cf)
#pragma unroll
    for (int kf = 0; kf < 2; ++kf) {
      const int cfg = (nbase >> 4) + nw * 4 + cf;
      aW[cf][kf] = *reinterpret_cast<const short8*>(
          wsW + ((size_t)(cfg * 2 + kf) * 64 + lane) * 8);
    }

  short8 bX[2][2];
#pragma unroll
  for (int rf = 0; rf < 2; ++rf)
#pragma unroll
    for (int kf = 0; kf < 2; ++kf) {
      const int row = mbase + mw * 32 + rf * 16 + L15;
      bX[rf][kf] = *reinterpret_cast<const short8*>(
          wsX + (size_t)row * 64 + kf * 32 + g * 8);
    }

  f32x4 acc[4][2];
#pragma unroll
  for (int cf = 0; cf < 4; ++cf)
#pragma unroll
    for (int rf = 0; rf < 2; ++rf) {
      f32x4 c = {0.f, 0.f, 0.f, 0.f};
      c = __builtin_amdgcn_mfma_f32_16x16x32_bf16(aW[cf][0], bX[rf][0], c, 0, 0, 0);
      c = __builtin_amdgcn_mfma_f32_16x16x32_bf16(aW[cf][1], bX[rf][1], c, 0, 0, 0);
      acc[cf][rf] = c;
    }

  float Sw = 0.f;
#pragma unroll
  for (int i = 0; i < 8; ++i) Sw += w_seg[i];
  const float s1w = 1.f + Sw;
  const float bseg = b_seg[0];
  const float tseg = w_seg[lane & 7];

  const float inv2pi = 0.15915494309189535f;
  const float KLOG = 0.02595256324130752f;  // log2(10000)/512
  float dv[4][2];
#pragma unroll
  for (int cf = 0; cf < 4; ++cf) {
    const int p = (nbase + nw * 64 + cf * 16 + g * 4) >> 1;
    dv[cf][0] = exp2f(-(float)p * KLOG) * inv2pi;
    dv[cf][1] = exp2f(-(float)(p + 1) * KLOG) * inv2pi;
  }

#pragma unroll
  for (int cf = 0; cf < 4; ++cf) {
    const int colq = nbase + nw * 64 + cf * 16 + g * 4;
    const float4 eb = *reinterpret_cast<const float4*>(b_emb + colq);
    const float e0 = eb.x * s1w + bseg, e1 = eb.y * s1w + bseg;
    const float e2 = eb.z * s1w + bseg, e3 = eb.w * s1w + bseg;
#pragma unroll
    for (int rf = 0; rf < 2; ++rf) {
      f32x4 a = acc[cf][rf];
      float q0 = a[0] * tseg, q1 = a[1] * tseg, q2 = a[2] * tseg, q3 = a[3] * tseg;
      q0 += __shfl_xor(q0, 1); q1 += __shfl_xor(q1, 1);
      q2 += __shfl_xor(q2, 1); q3 += __shfl_xor(q3, 1);
      q0 += __shfl_xor(q0, 2); q1 += __shfl_xor(q1, 2);
      q2 += __shfl_xor(q2, 2); q3 += __shfl_xor(q3, 2);
      q0 += __shfl_xor(q0, 4); q1 += __shfl_xor(q1, 4);
      q2 += __shfl_xor(q2, 4); q3 += __shfl_xor(q3, 4);

      const int row = mbase + mw * 32 + rf * 16 + L15;
      const float s = (float)(row & 511);
      const float pe0 = __builtin_amdgcn_sinf(__builtin_amdgcn_fractf(s * dv[cf][0]));
      const float pe1 = __builtin_amdgcn_sinf(__builtin_amdgcn_fractf(s * dv[cf][0] + 0.25f));
      const float pe2 = __builtin_amdgcn_sinf(__builtin_amdgcn_fractf(s * dv[cf][1]));
      const float pe3 = __builtin_amdgcn_sinf(__builtin_amdgcn_fractf(s * dv[cf][1] + 0.25f));

      float4 o;
      o.x = a[0] + q0 + pe0 + e0;
      o.y = a[1] + q1 + pe1 + e1;
      o.z = a[2] + q2 + pe2 + e2;
      o.w = a[3] + q3 + pe3 + e3;
      *reinterpret_cast<float4*>(out + (size_t)row * D_DIM + colq) = o;
    }
  }
}

extern "C" void kernel_launch(void* const* d_in, const int* in_sizes, int n_in,
                              void* d_out, int out_size, void* d_ws,
                              size_t ws_size, hipStream_t stream) {
  const float* x = (const float*)d_in[0];
  const float* W = (const float*)d_in[1];
  const float* b_emb = (const float*)d_in[2];
  const float* w_seg = (const float*)d_in[3];
  const float* b_seg = (const float*)d_in[4];
  float* out = (float*)d_out;

  unsigned short* wsW = (unsigned short*)d_ws;                      // 128 KB
  unsigned short* wsX = (unsigned short*)((char*)d_ws + WS_X_OFF);  // 4 MB

  bert_setup<<<1056, 256, 0, stream>>>(x, W, wsW, wsX);
  // DIAGNOSTIC: main launched twice (idempotent). dur(R9) - dur(R4) isolates
  // the true HW cost of one main pass from fixed replay overhead.
  bert_main<<<4096, 256, 0, stream>>>(wsX, wsW, b_emb, w_seg, b_seg, out);
  bert_main<<<4096, 256, 0, stream>>>(wsX, wsW, b_emb, w_seg, b_seg, out);
}